// Round 1
// baseline (1453.424 us; speedup 1.0000x reference)
//
#include <hip/hip_runtime.h>
#include <hip/hip_bf16.h>

// Problem constants (fixed by setup_inputs)
#define BB 2
#define LL 4096
#define HH 32
#define DV 64
#define DQK 128
#define CC 64            // chunk size
#define NN 64            // number of chunks = LL/CC
#define MIMO_RANK 4.0f

// ---------------------------------------------------------------------------
// K1: full-sequence inclusive prefix sum of dt over l, per (b,h).
// One block per (b,h); 256 threads x 16 elements each.
// ---------------------------------------------------------------------------
__global__ __launch_bounds__(256) void k_scan_dt(const float* __restrict__ dt,
                                                 float* __restrict__ ang) {
    int bh = blockIdx.x;
    int b = bh / HH, h = bh % HH;
    int tid = threadIdx.x;
    const int PT = LL / 256;  // 16
    float v[PT];
    float s = 0.f;
    int tbase = tid * PT;
    for (int i = 0; i < PT; ++i) {
        v[i] = dt[(((size_t)b * LL + tbase + i) * HH) + h];
        s += v[i];
    }
    // inclusive wave scan (wave = 64)
    int lane = tid & 63, wv = tid >> 6;
    float ps = s;
    for (int off = 1; off < 64; off <<= 1) {
        float o = __shfl_up(ps, off, 64);
        if (lane >= off) ps += o;
    }
    __shared__ float wsum[4];
    if (lane == 63) wsum[wv] = ps;
    __syncthreads();
    float wadd = 0.f;
    for (int w = 0; w < wv; ++w) wadd += wsum[w];
    float run = wadd + ps - s;  // exclusive prefix for this thread
    for (int i = 0; i < PT; ++i) {
        run += v[i];
        ang[(((size_t)b * LL + tbase + i) * HH) + h] = run;
    }
}

// ---------------------------------------------------------------------------
// K2: per-(b,n,h) intra-chunk tile.
//  - rotary(q,k) into LDS
//  - SL[t][s] = (t>=s) ? exp(A*(ang_t-ang_s)) * <rq_t, rk_s> : 0
//  - y_intra[t][e] = sum_s SL*u  -> d_out (raw, finalized by K4)
//  - dH[d][e] = sum_s rk[s][d]*exp(A*(ang_end-ang_s))*u[s][e] -> ws
//  - cdecay[b,n,h] = exp(A*(ang_end-ang_prevchunk))
// ---------------------------------------------------------------------------
__global__ __launch_bounds__(256) void k_intra(
    const float* __restrict__ x, const float* __restrict__ dt,
    const float* __restrict__ A, const float* __restrict__ Bg,
    const float* __restrict__ Cg, const float* __restrict__ ang,
    float* __restrict__ out, float* __restrict__ dH,
    float* __restrict__ cdecay) {
    int n = blockIdx.x, h = blockIdx.y, b = blockIdx.z;
    int tid = threadIdx.x;
    int t0 = n * CC;

    __shared__ float rq[CC][DQK + 1];
    __shared__ float rk[CC][DQK + 1];
    __shared__ float uu[CC][DV + 1];
    __shared__ float SL[CC][CC + 1];
    __shared__ float angs[CC], cs[CC], ss[CC], dts[CC], dws[CC];
    __shared__ float angPrev_s;

    float Ah = A[h];

    if (tid < CC) {
        float a = ang[(((size_t)b * LL + t0 + tid) * HH) + h];
        angs[tid] = a;
        float cv, sv;
        sincosf(a, &sv, &cv);
        cs[tid] = cv;
        ss[tid] = sv;
        dts[tid] = dt[(((size_t)b * LL + t0 + tid) * HH) + h];
    }
    if (tid == 0)
        angPrev_s = (t0 == 0) ? 0.f : ang[(((size_t)b * LL + t0 - 1) * HH) + h];
    __syncthreads();

    if (tid < CC) dws[tid] = __expf(0.f) * expf(Ah * (angs[CC - 1] - angs[tid]));
    if (tid == 0)
        cdecay[(b * NN + n) * HH + h] = expf(Ah * (angs[CC - 1] - angPrev_s));

    // rotary q (from C_gate) and k (from B_gate)
    for (int idx = tid; idx < CC * DQK; idx += 256) {
        int t = idx >> 7, d = idx & 127;
        int dl = d & 63;
        size_t base = ((size_t)b * LL + t0 + t) * DQK;
        float cv = cs[t], sv = ss[t];
        float q1 = Cg[base + dl], q2 = Cg[base + dl + 64];
        float k1 = Bg[base + dl], k2 = Bg[base + dl + 64];
        rq[t][d] = (d < 64) ? (q1 * cv - q2 * sv) : (q1 * sv + q2 * cv);
        rk[t][d] = (d < 64) ? (k1 * cv - k2 * sv) : (k1 * sv + k2 * cv);
    }
    // u = dt * x
    for (int idx = tid; idx < CC * DV; idx += 256) {
        int s_ = idx >> 6, e = idx & 63;
        uu[s_][e] = dts[s_] * x[((((size_t)b * LL + t0 + s_) * HH) + h) * DV + e];
    }
    __syncthreads();

    // S * L  (only lower triangle needed)
    for (int idx = tid; idx < CC * CC; idx += 256) {
        int t = idx >> 6, s_ = idx & 63;
        float val = 0.f;
        if (t >= s_) {
            float acc = 0.f;
            for (int d = 0; d < DQK; ++d) acc += rq[t][d] * rk[s_][d];
            val = acc * expf(Ah * (angs[t] - angs[s_]));
        }
        SL[t][s_] = val;
    }
    __syncthreads();

    // y_intra -> out (raw)
    for (int idx = tid; idx < CC * DV; idx += 256) {
        int t = idx >> 6, e = idx & 63;
        float acc = 0.f;
        for (int s_ = 0; s_ <= t; ++s_) acc += SL[t][s_] * uu[s_][e];
        out[((((size_t)b * LL + t0 + t) * HH) + h) * DV + e] = acc;
    }
    __syncthreads();

    // scale u rows by decay-to-end, in place
    for (int idx = tid; idx < CC * DV; idx += 256) {
        int s_ = idx >> 6, e = idx & 63;
        uu[s_][e] *= dws[s_];
    }
    __syncthreads();

    // dH[d][e] = sum_s rk[s][d] * uw[s][e]
    float* dHp = dH + (((size_t)(b * NN + n) * HH) + h) * (DQK * DV);
    for (int idx = tid; idx < DQK * DV; idx += 256) {
        int d = idx >> 6, e = idx & 63;
        float acc = 0.f;
        for (int s_ = 0; s_ < CC; ++s_) acc += rk[s_][d] * uu[s_][e];
        dHp[idx] = acc;
    }
}

// ---------------------------------------------------------------------------
// K3: sequential chunk scan, in place on the dH buffer.
// One thread per (b,h,d,e); loop over n. After this kernel the buffer holds
// Hprev[n] (state BEFORE chunk n is applied).
// dH layout: [b][n][h][d][e], strides: b:2^24, n:2^18, h:2^13, d:2^6, e:1
// ---------------------------------------------------------------------------
__global__ __launch_bounds__(256) void k_scan_chunks(
    float* __restrict__ dH, const float* __restrict__ cdecay) {
    size_t f = (size_t)blockIdx.x * 256 + threadIdx.x;  // 0..524287
    int b = (int)(f >> 18);
    int r = (int)(f & 0x3FFFF);
    int h = (int)((f >> 13) & 31);
    size_t base = ((size_t)b << 24) + (size_t)r;
    const float* cd = cdecay + (size_t)(b * NN) * HH + h;
    float Hacc = 0.f;
    for (int n = 0; n < NN; ++n) {
        size_t a = base + ((size_t)n << 18);
        float v = dH[a];
        dH[a] = Hacc;           // Hprev for chunk n
        Hacc = cd[n * HH] * Hacc + v;
    }
}

// ---------------------------------------------------------------------------
// K4: y_inter + final combine.
// y_inter[t][e] = exp(cum_t) * sum_d rq[t][d] * Hprev[d][e]
// out = MIMO_RANK*(intra + inter) + D[h]*x
// ---------------------------------------------------------------------------
__global__ __launch_bounds__(256) void k_inter(
    const float* __restrict__ x, const float* __restrict__ A,
    const float* __restrict__ Dd, const float* __restrict__ Cg,
    const float* __restrict__ ang, const float* __restrict__ Hprev,
    float* __restrict__ out) {
    int n = blockIdx.x, h = blockIdx.y, b = blockIdx.z;
    int tid = threadIdx.x;
    int t0 = n * CC;

    __shared__ float rq[CC][DQK + 1];
    __shared__ float Hp[DQK][DV + 1];
    __shared__ float cs[CC], ss[CC], gs[CC];
    __shared__ float angs[CC];
    __shared__ float angPrev_s;

    float Ah = A[h];
    if (tid < CC) {
        float a = ang[(((size_t)b * LL + t0 + tid) * HH) + h];
        angs[tid] = a;
        float cv, sv;
        sincosf(a, &sv, &cv);
        cs[tid] = cv;
        ss[tid] = sv;
    }
    if (tid == 0)
        angPrev_s = (t0 == 0) ? 0.f : ang[(((size_t)b * LL + t0 - 1) * HH) + h];
    __syncthreads();
    if (tid < CC) gs[tid] = expf(Ah * (angs[tid] - angPrev_s));

    // rotary q
    for (int idx = tid; idx < CC * DQK; idx += 256) {
        int t = idx >> 7, d = idx & 127;
        int dl = d & 63;
        size_t base = ((size_t)b * LL + t0 + t) * DQK;
        float cv = cs[t], sv = ss[t];
        float q1 = Cg[base + dl], q2 = Cg[base + dl + 64];
        rq[t][d] = (d < 64) ? (q1 * cv - q2 * sv) : (q1 * sv + q2 * cv);
    }
    // load Hprev tile
    const float* Hsrc = Hprev + (((size_t)(b * NN + n) * HH) + h) * (DQK * DV);
    for (int idx = tid; idx < DQK * DV; idx += 256) {
        int d = idx >> 6, e = idx & 63;
        Hp[d][e] = Hsrc[idx];
    }
    __syncthreads();

    float Dh = Dd[h];
    for (int idx = tid; idx < CC * DV; idx += 256) {
        int t = idx >> 6, e = idx & 63;
        float acc = 0.f;
        for (int d = 0; d < DQK; ++d) acc += rq[t][d] * Hp[d][e];
        size_t oidx = ((((size_t)b * LL + t0 + t) * HH) + h) * DV + e;
        float intra = out[oidx];
        float xval = x[oidx];
        out[oidx] = MIMO_RANK * (intra + gs[t] * acc) + Dh * xval;
    }
}

// ---------------------------------------------------------------------------
extern "C" void kernel_launch(void* const* d_in, const int* in_sizes, int n_in,
                              void* d_out, int out_size, void* d_ws,
                              size_t ws_size, hipStream_t stream) {
    (void)in_sizes; (void)n_in; (void)out_size; (void)ws_size;
    const float* x  = (const float*)d_in[0];
    const float* dt = (const float*)d_in[1];
    const float* A  = (const float*)d_in[2];
    const float* Bg = (const float*)d_in[3];
    const float* Cg = (const float*)d_in[4];
    const float* Dd = (const float*)d_in[5];
    float* out = (float*)d_out;
    float* ws  = (float*)d_ws;

    float* ang    = ws;                    // B*L*H            = 262144 f32
    float* cdecay = ws + 262144;           // B*N*H            = 4096 f32
    float* dH     = ws + 266240;           // B*N*H*DQK*DV     = 33554432 f32

    k_scan_dt<<<BB * HH, 256, 0, stream>>>(dt, ang);
    k_intra<<<dim3(NN, HH, BB), 256, 0, stream>>>(x, dt, A, Bg, Cg, ang, out,
                                                  dH, cdecay);
    k_scan_chunks<<<(BB * HH * DQK * DV) / 256, 256, 0, stream>>>(dH, cdecay);
    k_inter<<<dim3(NN, HH, BB), 256, 0, stream>>>(x, A, Dd, Cg, ang, dH, out);
}

// Round 2
// 234.656 us; speedup vs baseline: 6.1939x; 6.1939x over previous
//
#include <hip/hip_runtime.h>
#include <hip/hip_bf16.h>

// Problem constants (fixed by setup_inputs)
#define BB 2
#define LL 4096
#define HH 32
#define DV 64
#define DQK 128
#define CC 64            // chunk size
#define NN 64            // number of chunks = LL/CC
#define MIMO_RANK 4.0f

typedef __attribute__((ext_vector_type(8))) short short8;
typedef __attribute__((ext_vector_type(4))) float f32x4;

__device__ __forceinline__ short f2bf(float f) {
    __hip_bfloat16 h = __float2bfloat16(f);
    return *reinterpret_cast<short*>(&h);
}

// ---------------------------------------------------------------------------
// K1: full-sequence inclusive prefix sum of dt over l, per (b,h).
// ---------------------------------------------------------------------------
__global__ __launch_bounds__(256) void k_scan_dt(const float* __restrict__ dt,
                                                 float* __restrict__ ang) {
    int bh = blockIdx.x;
    int b = bh / HH, h = bh % HH;
    int tid = threadIdx.x;
    const int PT = LL / 256;  // 16
    float v[PT];
    float s = 0.f;
    int tbase = tid * PT;
    for (int i = 0; i < PT; ++i) {
        v[i] = dt[(((size_t)b * LL + tbase + i) * HH) + h];
        s += v[i];
    }
    int lane = tid & 63, wv = tid >> 6;
    float ps = s;
    for (int off = 1; off < 64; off <<= 1) {
        float o = __shfl_up(ps, off, 64);
        if (lane >= off) ps += o;
    }
    __shared__ float wsum[4];
    if (lane == 63) wsum[wv] = ps;
    __syncthreads();
    float wadd = 0.f;
    for (int w = 0; w < wv; ++w) wadd += wsum[w];
    float run = wadd + ps - s;  // exclusive prefix for this thread
    for (int i = 0; i < PT; ++i) {
        run += v[i];
        ang[(((size_t)b * LL + tbase + i) * HH) + h] = run;
    }
}

// ---------------------------------------------------------------------------
// K2: per-(b,n,h) intra-chunk tile, MFMA version.
// Matmuls via mfma_f32_16x16x32_bf16.
//   S^T[s][t]  : A = rk[s][d], B = rq[t][d]            (K = d = 128)
//   y_intra    : A = SL[t][s], B = uwT[e][s]           (K = s = 64)
//   dH[d][e]   : A = rkT[d][s], B = uwT[e][s]          (K = s = 64)
// SL[t][s] = mask(t>=s) * S * exp(Ah*(ang_t - ang_end))   (bf16)
// uwT[e][s] = dt_s * x[s][e] * exp(Ah*(ang_end - ang_s))  (bf16)
// so SL.uw reproduces S * exp(Ah*(ang_t-ang_s)) * u exactly (factorization).
// ---------------------------------------------------------------------------
__global__ __launch_bounds__(256) void k_intra(
    const float* __restrict__ x, const float* __restrict__ dt,
    const float* __restrict__ A, const float* __restrict__ Bg,
    const float* __restrict__ Cg, const float* __restrict__ ang,
    float* __restrict__ out, float* __restrict__ dH,
    float* __restrict__ cdecay) {
    int n = blockIdx.x, h = blockIdx.y, b = blockIdx.z;
    int tid = threadIdx.x;
    int t0 = n * CC;

    // +8 bf16 row padding: row stride = 4 banks -> 2-way conflict (free)
    __shared__ __align__(16) short rq[CC][DQK + 8];    // [t][d]
    __shared__ __align__(16) short rk[CC][DQK + 8];    // [s][d]
    __shared__ __align__(16) short rkT[DQK][CC + 8];   // [d][s]
    __shared__ __align__(16) short uwT[DV][CC + 8];    // [e][s]
    __shared__ __align__(16) short SL[CC][CC + 8];     // [t][s]
    __shared__ float angs[CC], cs[CC], ss[CC], dts[CC], dws[CC], et[CC];
    __shared__ float angPrev_s;

    float Ah = A[h];

    if (tid < CC) {
        float a = ang[(((size_t)b * LL + t0 + tid) * HH) + h];
        angs[tid] = a;
        float cv, sv;
        sincosf(a, &sv, &cv);
        cs[tid] = cv;
        ss[tid] = sv;
        dts[tid] = dt[(((size_t)b * LL + t0 + tid) * HH) + h];
    }
    if (tid == 0)
        angPrev_s = (t0 == 0) ? 0.f : ang[(((size_t)b * LL + t0 - 1) * HH) + h];
    __syncthreads();

    if (tid < CC) {
        float aend = angs[CC - 1];
        dws[tid] = expf(Ah * (aend - angs[tid]));   // decay-to-end (<=1)
        et[tid]  = expf(Ah * (angs[tid] - aend));   // inverse factor (>=1)
    }
    if (tid == 0)
        cdecay[(b * NN + n) * HH + h] = expf(Ah * (angs[CC - 1] - angPrev_s));

    // rotary q (from C_gate) and k (from B_gate) -> bf16 LDS
    for (int idx = tid; idx < CC * DQK; idx += 256) {
        int t = idx >> 7, d = idx & 127, dl = d & 63;
        size_t gb = ((size_t)b * LL + t0 + t) * DQK;
        float cv = cs[t], sv = ss[t];
        float q1 = Cg[gb + dl], q2 = Cg[gb + dl + 64];
        float k1 = Bg[gb + dl], k2 = Bg[gb + dl + 64];
        float rqv = (d < 64) ? (q1 * cv - q2 * sv) : (q1 * sv + q2 * cv);
        float rkv = (d < 64) ? (k1 * cv - k2 * sv) : (k1 * sv + k2 * cv);
        rq[t][d] = f2bf(rqv);
        rk[t][d] = f2bf(rkv);
        rkT[d][t] = f2bf(rkv);
    }
    __syncthreads();  // dws ready, rotary ready

    // uw = dt * x * decay_to_end, stored transposed [e][s]
    for (int idx = tid; idx < CC * DV; idx += 256) {
        int s_ = idx >> 6, e = idx & 63;
        float uv = dts[s_] * x[((((size_t)b * LL + t0 + s_) * HH) + h) * DV + e] * dws[s_];
        uwT[e][s_] = f2bf(uv);
    }
    __syncthreads();

    int wv = tid >> 6, lane = tid & 63;
    int lrow = lane & 15;            // A/B non-K index selector
    int kgrp = (lane >> 4) * 8;      // K offset within a 32-step
    int orow = (lane >> 4) * 4;      // C/D row base

    // ---- Phase 1: S^T (64x64, K=128). Wave w owns s-rows [16w,16w+16). ----
    f32x4 accS[4] = {{0.f,0.f,0.f,0.f},{0.f,0.f,0.f,0.f},{0.f,0.f,0.f,0.f},{0.f,0.f,0.f,0.f}};
    {
        const short* arow = &rk[16 * wv + lrow][0];
        #pragma unroll
        for (int k0 = 0; k0 < DQK; k0 += 32) {
            short8 a = *(const short8*)(arow + k0 + kgrp);
            #pragma unroll
            for (int nt = 0; nt < 4; ++nt) {
                short8 bf = *(const short8*)(&rq[16 * nt + lrow][0] + k0 + kgrp);
                accS[nt] = __builtin_amdgcn_mfma_f32_16x16x32_bf16(a, bf, accS[nt], 0, 0, 0);
            }
        }
    }
    // mask + scale + store SL[t][s] (bf16). Output of S^T: row=s, col=t.
    #pragma unroll
    for (int nt = 0; nt < 4; ++nt) {
        int t = 16 * nt + lrow;
        float etv = et[t];
        #pragma unroll
        for (int r = 0; r < 4; ++r) {
            int s_ = 16 * wv + orow + r;
            float v = (t >= s_) ? accS[nt][r] * etv : 0.f;
            SL[t][s_] = f2bf(v);
        }
    }
    __syncthreads();

    // ---- Phase 2: y_intra = SL . uw^T  (64x64, K=64) ----
    {
        f32x4 accY[4] = {{0.f,0.f,0.f,0.f},{0.f,0.f,0.f,0.f},{0.f,0.f,0.f,0.f},{0.f,0.f,0.f,0.f}};
        const short* arow = &SL[16 * wv + lrow][0];
        #pragma unroll
        for (int k0 = 0; k0 < CC; k0 += 32) {
            short8 a = *(const short8*)(arow + k0 + kgrp);
            #pragma unroll
            for (int nt = 0; nt < 4; ++nt) {
                short8 bf = *(const short8*)(&uwT[16 * nt + lrow][0] + k0 + kgrp);
                accY[nt] = __builtin_amdgcn_mfma_f32_16x16x32_bf16(a, bf, accY[nt], 0, 0, 0);
            }
        }
        #pragma unroll
        for (int nt = 0; nt < 4; ++nt) {
            int e = 16 * nt + lrow;
            #pragma unroll
            for (int r = 0; r < 4; ++r) {
                int t = 16 * wv + orow + r;
                out[((((size_t)b * LL + t0 + t) * HH) + h) * DV + e] = accY[nt][r];
            }
        }
    }

    // ---- Phase 3: dH = rkT . uw^T  (128x64, K=64). Wave w owns d [32w,32w+32). ----
    {
        f32x4 accH[2][4] = {{{0.f,0.f,0.f,0.f},{0.f,0.f,0.f,0.f},{0.f,0.f,0.f,0.f},{0.f,0.f,0.f,0.f}},
                            {{0.f,0.f,0.f,0.f},{0.f,0.f,0.f,0.f},{0.f,0.f,0.f,0.f},{0.f,0.f,0.f,0.f}}};
        #pragma unroll
        for (int k0 = 0; k0 < CC; k0 += 32) {
            #pragma unroll
            for (int mt = 0; mt < 2; ++mt) {
                short8 a = *(const short8*)(&rkT[32 * wv + 16 * mt + lrow][0] + k0 + kgrp);
                #pragma unroll
                for (int nt = 0; nt < 4; ++nt) {
                    short8 bf = *(const short8*)(&uwT[16 * nt + lrow][0] + k0 + kgrp);
                    accH[mt][nt] = __builtin_amdgcn_mfma_f32_16x16x32_bf16(a, bf, accH[mt][nt], 0, 0, 0);
                }
            }
        }
        float* dHp = dH + (((size_t)(b * NN + n) * HH) + h) * (DQK * DV);
        #pragma unroll
        for (int mt = 0; mt < 2; ++mt)
            #pragma unroll
            for (int nt = 0; nt < 4; ++nt) {
                int e = 16 * nt + lrow;
                #pragma unroll
                for (int r = 0; r < 4; ++r) {
                    int d = 32 * wv + 16 * mt + orow + r;
                    dHp[d * DV + e] = accH[mt][nt][r];
                }
            }
    }
}

// ---------------------------------------------------------------------------
// K3: sequential chunk scan, in place on the dH buffer.
// ---------------------------------------------------------------------------
__global__ __launch_bounds__(256) void k_scan_chunks(
    float* __restrict__ dH, const float* __restrict__ cdecay) {
    size_t f = (size_t)blockIdx.x * 256 + threadIdx.x;  // 0..524287
    int b = (int)(f >> 18);
    int r = (int)(f & 0x3FFFF);
    int h = (int)((f >> 13) & 31);
    size_t base = ((size_t)b << 24) + (size_t)r;
    const float* cd = cdecay + (size_t)(b * NN) * HH + h;
    float Hacc = 0.f;
    for (int n = 0; n < NN; ++n) {
        size_t a = base + ((size_t)n << 18);
        float v = dH[a];
        dH[a] = Hacc;           // Hprev for chunk n
        Hacc = cd[n * HH] * Hacc + v;
    }
}

// ---------------------------------------------------------------------------
// K4: y_inter + final combine (MFMA).
// y_inter = rq(64x128) . Hprev(128x64):  A = rq[t][d], B = HpT[e][d]
// out = MIMO_RANK*(intra + exp(cum_t)*inter) + D[h]*x
// ---------------------------------------------------------------------------
__global__ __launch_bounds__(256) void k_inter(
    const float* __restrict__ x, const float* __restrict__ A,
    const float* __restrict__ Dd, const float* __restrict__ Cg,
    const float* __restrict__ ang, const float* __restrict__ Hprev,
    float* __restrict__ out) {
    int n = blockIdx.x, h = blockIdx.y, b = blockIdx.z;
    int tid = threadIdx.x;
    int t0 = n * CC;

    __shared__ __align__(16) short rq[CC][DQK + 8];   // [t][d]
    __shared__ __align__(16) short HpT[DV][DQK + 8];  // [e][d]
    __shared__ float cs[CC], ss[CC], gs[CC], angs[CC];
    __shared__ float angPrev_s;

    float Ah = A[h];
    if (tid < CC) {
        float a = ang[(((size_t)b * LL + t0 + tid) * HH) + h];
        angs[tid] = a;
        float cv, sv;
        sincosf(a, &sv, &cv);
        cs[tid] = cv;
        ss[tid] = sv;
    }
    if (tid == 0)
        angPrev_s = (t0 == 0) ? 0.f : ang[(((size_t)b * LL + t0 - 1) * HH) + h];
    __syncthreads();
    if (tid < CC) gs[tid] = expf(Ah * (angs[tid] - angPrev_s));

    for (int idx = tid; idx < CC * DQK; idx += 256) {
        int t = idx >> 7, d = idx & 127, dl = d & 63;
        size_t gb = ((size_t)b * LL + t0 + t) * DQK;
        float cv = cs[t], sv = ss[t];
        float q1 = Cg[gb + dl], q2 = Cg[gb + dl + 64];
        rq[t][d] = f2bf((d < 64) ? (q1 * cv - q2 * sv) : (q1 * sv + q2 * cv));
    }
    const float* Hsrc = Hprev + (((size_t)(b * NN + n) * HH) + h) * (DQK * DV);
    for (int idx = tid; idx < DQK * DV; idx += 256) {
        int d = idx >> 6, e = idx & 63;
        HpT[e][d] = f2bf(Hsrc[idx]);
    }
    __syncthreads();

    int wv = tid >> 6, lane = tid & 63;
    int lrow = lane & 15;
    int kgrp = (lane >> 4) * 8;
    int orow = (lane >> 4) * 4;

    f32x4 accI[4] = {{0.f,0.f,0.f,0.f},{0.f,0.f,0.f,0.f},{0.f,0.f,0.f,0.f},{0.f,0.f,0.f,0.f}};
    const short* arow = &rq[16 * wv + lrow][0];
    #pragma unroll
    for (int k0 = 0; k0 < DQK; k0 += 32) {
        short8 a = *(const short8*)(arow + k0 + kgrp);
        #pragma unroll
        for (int nt = 0; nt < 4; ++nt) {
            short8 bf = *(const short8*)(&HpT[16 * nt + lrow][0] + k0 + kgrp);
            accI[nt] = __builtin_amdgcn_mfma_f32_16x16x32_bf16(a, bf, accI[nt], 0, 0, 0);
        }
    }

    float Dh = Dd[h];
    #pragma unroll
    for (int nt = 0; nt < 4; ++nt) {
        int e = 16 * nt + lrow;
        #pragma unroll
        for (int r = 0; r < 4; ++r) {
            int t = 16 * wv + orow + r;
            size_t oidx = ((((size_t)b * LL + t0 + t) * HH) + h) * DV + e;
            float intra = out[oidx];
            out[oidx] = MIMO_RANK * (intra + gs[t] * accI[nt][r]) + Dh * x[oidx];
        }
    }
}

// ---------------------------------------------------------------------------
extern "C" void kernel_launch(void* const* d_in, const int* in_sizes, int n_in,
                              void* d_out, int out_size, void* d_ws,
                              size_t ws_size, hipStream_t stream) {
    (void)in_sizes; (void)n_in; (void)out_size; (void)ws_size;
    const float* x  = (const float*)d_in[0];
    const float* dt = (const float*)d_in[1];
    const float* A  = (const float*)d_in[2];
    const float* Bg = (const float*)d_in[3];
    const float* Cg = (const float*)d_in[4];
    const float* Dd = (const float*)d_in[5];
    float* out = (float*)d_out;
    float* ws  = (float*)d_ws;

    float* ang    = ws;                    // B*L*H            = 262144 f32
    float* cdecay = ws + 262144;           // B*N*H            = 4096 f32
    float* dH     = ws + 266240;           // B*N*H*DQK*DV     = 33554432 f32

    k_scan_dt<<<BB * HH, 256, 0, stream>>>(dt, ang);
    k_intra<<<dim3(NN, HH, BB), 256, 0, stream>>>(x, dt, A, Bg, Cg, ang, out,
                                                  dH, cdecay);
    k_scan_chunks<<<(BB * HH * DQK * DV) / 256, 256, 0, stream>>>(dH, cdecay);
    k_inter<<<dim3(NN, HH, BB), 256, 0, stream>>>(x, A, Dd, Cg, ang, dH, out);
}

// Round 3
// 140.328 us; speedup vs baseline: 10.3574x; 1.6722x over previous
//
#include <hip/hip_runtime.h>
#include <hip/hip_bf16.h>

// Problem constants (fixed by setup_inputs)
#define BB 2
#define LL 4096
#define HH 32
#define DV 64
#define DQK 128
#define CC 64            // chunk size
#define NN 64            // number of chunks = LL/CC
#define MIMO_RANK 4.0f

typedef __attribute__((ext_vector_type(8))) short short8;
typedef __attribute__((ext_vector_type(4))) float f32x4;

__device__ __forceinline__ ushort f2bf(float f) {
    uint u = __float_as_uint(f);
    u += 0x7FFF + ((u >> 16) & 1);   // RNE
    return (ushort)(u >> 16);
}
__device__ __forceinline__ float bfbits2f(uint lo16) {
    return __uint_as_float(lo16 << 16);
}
__device__ __forceinline__ uint packbf2(float a, float b) {
    return (uint)f2bf(a) | ((uint)f2bf(b) << 16);
}

// Build the 4 A-fragments (K=128) of a rotary-transformed row directly in
// registers: lane owns row t, k-slice kgrp..kgrp+8 per 32-step.
__device__ __forceinline__ void make_rot_frags(const float* __restrict__ G,
                                               size_t gb, float cv, float sv,
                                               int kgrp, short8* fr) {
    #pragma unroll
    for (int kk = 0; kk < 4; ++kk) {
        int d0 = kk * 32 + kgrp;     // 8-aligned, entirely in one half
        int dl = d0 & 63;
        bool low = d0 < 64;
        float4 a1 = *(const float4*)(G + gb + dl);
        float4 b1 = *(const float4*)(G + gb + dl + 4);
        float4 a2 = *(const float4*)(G + gb + dl + 64);
        float4 b2 = *(const float4*)(G + gb + dl + 68);
        float v0, v1, v2, v3, v4, v5, v6, v7;
        if (low) {
            v0 = a1.x * cv - a2.x * sv; v1 = a1.y * cv - a2.y * sv;
            v2 = a1.z * cv - a2.z * sv; v3 = a1.w * cv - a2.w * sv;
            v4 = b1.x * cv - b2.x * sv; v5 = b1.y * cv - b2.y * sv;
            v6 = b1.z * cv - b2.z * sv; v7 = b1.w * cv - b2.w * sv;
        } else {
            v0 = a1.x * sv + a2.x * cv; v1 = a1.y * sv + a2.y * cv;
            v2 = a1.z * sv + a2.z * cv; v3 = a1.w * sv + a2.w * cv;
            v4 = b1.x * sv + b2.x * cv; v5 = b1.y * sv + b2.y * cv;
            v6 = b1.z * sv + b2.z * cv; v7 = b1.w * sv + b2.w * cv;
        }
        short8 r;
        r[0] = (short)f2bf(v0); r[1] = (short)f2bf(v1);
        r[2] = (short)f2bf(v2); r[3] = (short)f2bf(v3);
        r[4] = (short)f2bf(v4); r[5] = (short)f2bf(v5);
        r[6] = (short)f2bf(v6); r[7] = (short)f2bf(v7);
        fr[kk] = r;
    }
}

// ---------------------------------------------------------------------------
// K1: full-sequence inclusive prefix sum of dt over l, per (b,h).
// ---------------------------------------------------------------------------
__global__ __launch_bounds__(256) void k_scan_dt(const float* __restrict__ dt,
                                                 float* __restrict__ ang) {
    int bh = blockIdx.x;
    int b = bh / HH, h = bh % HH;
    int tid = threadIdx.x;
    const int PT = LL / 256;  // 16
    float v[PT];
    float s = 0.f;
    int tbase = tid * PT;
    for (int i = 0; i < PT; ++i) {
        v[i] = dt[(((size_t)b * LL + tbase + i) * HH) + h];
        s += v[i];
    }
    int lane = tid & 63, wv = tid >> 6;
    float ps = s;
    for (int off = 1; off < 64; off <<= 1) {
        float o = __shfl_up(ps, off, 64);
        if (lane >= off) ps += o;
    }
    __shared__ float wsum[4];
    if (lane == 63) wsum[wv] = ps;
    __syncthreads();
    float wadd = 0.f;
    for (int w = 0; w < wv; ++w) wadd += wsum[w];
    float run = wadd + ps - s;  // exclusive prefix for this thread
    for (int i = 0; i < PT; ++i) {
        run += v[i];
        ang[(((size_t)b * LL + tbase + i) * HH) + h] = run;
    }
}

// ---------------------------------------------------------------------------
// K2: per-(b,n,h) intra-chunk tile, MFMA.
//   S[t][s]   : A = rq frag (regs), B = rk[s] (swizzled LDS)     K=128
//   y_intra   : A = SL[t][s], B = uwT[e][s]                      K=64
//   dH[d][e]  : A = rkT[d][s], B = uwT[e][s]                     K=64
// out = 4*y_intra + D*x ; dH stored bf16, e-major [e][d] via LDS bounce.
// ---------------------------------------------------------------------------
__global__ __launch_bounds__(256, 3) void k_intra(
    const float* __restrict__ x, const float* __restrict__ dt,
    const float* __restrict__ A, const float* __restrict__ Bg,
    const float* __restrict__ Cg, const float* __restrict__ ang,
    const float* __restrict__ Dd,
    float* __restrict__ out, ushort* __restrict__ dH,
    float* __restrict__ cdecay) {
    int n = blockIdx.x, h = blockIdx.y, b = blockIdx.z;
    int tid = threadIdx.x;
    int t0 = n * CC;

    __shared__ ushort rk[CC][DQK];       // XOR-swizzled: 16B slot ^= (s&7)
    __shared__ ushort rkT[DQK][CC + 8];  // [d][s]; reused as dstage[64][136]
    __shared__ ushort uwT[DV][CC + 8];   // [e][s]
    __shared__ ushort SL[CC][CC + 8];    // [t][s]
    __shared__ float angs[CC], csv[CC], ssv[CC], dw2[CC];
    // total LDS = 16384 + 18432 + 9216 + 9216 + 1024 = 54272 B -> 3 blocks/CU

    float Ah = A[h];

    float my_dt = 0.f;
    if (tid < CC) {
        float a = ang[(((size_t)b * LL + t0 + tid) * HH) + h];
        angs[tid] = a;
        float sv, cv;
        __sincosf(a, &sv, &cv);
        csv[tid] = cv;
        ssv[tid] = sv;
        my_dt = dt[(((size_t)b * LL + t0 + tid) * HH) + h];
    }
    __syncthreads();
    float aend = angs[CC - 1];
    if (tid < CC) {
        dw2[tid] = my_dt * __expf(Ah * (aend - angs[tid]));  // dt * decay_to_end
    }
    if (tid == 0) {
        float angPrev = (t0 == 0) ? 0.f
                                  : ang[(((size_t)b * LL + t0 - 1) * HH) + h];
        cdecay[(b * NN + n) * HH + h] = __expf(Ah * (aend - angPrev));
    }

    // ---- stage rk (swizzled) + rkT ----
    for (int idx = tid; idx < CC * 16; idx += 256) {  // 4 iters
        int s = idx >> 4, d4 = (idx & 15) * 4;        // d4 in [0,64)
        size_t gb = ((size_t)b * LL + t0 + s) * DQK;
        float4 k1 = *(const float4*)(Bg + gb + d4);
        float4 k2 = *(const float4*)(Bg + gb + d4 + 64);
        float cv = csv[s], sv = ssv[s];
        ushort l0 = f2bf(k1.x * cv - k2.x * sv), l1 = f2bf(k1.y * cv - k2.y * sv);
        ushort l2 = f2bf(k1.z * cv - k2.z * sv), l3 = f2bf(k1.w * cv - k2.w * sv);
        ushort h0 = f2bf(k1.x * sv + k2.x * cv), h1 = f2bf(k1.y * sv + k2.y * cv);
        ushort h2 = f2bf(k1.z * sv + k2.z * cv), h3 = f2bf(k1.w * sv + k2.w * cv);
        int sx = s & 7;
        {
            ushort* dst = &rk[s][(((d4 >> 3) ^ sx) << 3) + (d4 & 7)];
            *(uint*)(dst) = (uint)l0 | ((uint)l1 << 16);
            *(uint*)(dst + 2) = (uint)l2 | ((uint)l3 << 16);
            int dh_ = d4 + 64;
            ushort* dst2 = &rk[s][(((dh_ >> 3) ^ sx) << 3) + (dh_ & 7)];
            *(uint*)(dst2) = (uint)h0 | ((uint)h1 << 16);
            *(uint*)(dst2 + 2) = (uint)h2 | ((uint)h3 << 16);
        }
        rkT[d4 + 0][s] = l0; rkT[d4 + 1][s] = l1;
        rkT[d4 + 2][s] = l2; rkT[d4 + 3][s] = l3;
        rkT[d4 + 64][s] = h0; rkT[d4 + 65][s] = h1;
        rkT[d4 + 66][s] = h2; rkT[d4 + 67][s] = h3;
    }
    __syncthreads();  // rk, rkT, dw2 visible

    // ---- stage uwT = dt * x * decay_to_end, [e][s] ----
    for (int idx = tid; idx < CC * 16; idx += 256) {  // 4 iters
        int s = idx >> 4, e4 = (idx & 15) * 4;
        float4 xv = *(const float4*)(x + ((((size_t)b * LL + t0 + s) * HH) + h) * DV + e4);
        float w = dw2[s];
        uwT[e4 + 0][s] = f2bf(xv.x * w);
        uwT[e4 + 1][s] = f2bf(xv.y * w);
        uwT[e4 + 2][s] = f2bf(xv.z * w);
        uwT[e4 + 3][s] = f2bf(xv.w * w);
    }

    int wv = tid >> 6, lane = tid & 63;
    int lrow = lane & 15;
    int kgrp = (lane >> 4) * 8;
    int orow = (lane >> 4) * 4;

    // ---- rq A-fragments in registers (wave wv owns t rows [16wv,16wv+16)) --
    int t_own = 16 * wv + lrow;
    short8 aq[4];
    make_rot_frags(Cg, ((size_t)b * LL + t0 + t_own) * DQK,
                   csv[t_own], ssv[t_own], kgrp, aq);

    // ---- Phase 1: S = rq . rk^T (m=t rows of this wave, n=s, K=128) ----
    f32x4 accS[4] = {{0.f,0.f,0.f,0.f},{0.f,0.f,0.f,0.f},
                     {0.f,0.f,0.f,0.f},{0.f,0.f,0.f,0.f}};
    #pragma unroll
    for (int kk = 0; kk < 4; ++kk) {
        int k16 = kk * 4 + (kgrp >> 3);   // 16B-slot index of this k-slice
        #pragma unroll
        for (int nt = 0; nt < 4; ++nt) {
            int s = 16 * nt + lrow;
            const ushort* bp = &rk[s][(k16 ^ (s & 7)) << 3];
            accS[nt] = __builtin_amdgcn_mfma_f32_16x16x32_bf16(
                aq[kk], *(const short8*)bp, accS[nt], 0, 0, 0);
        }
    }
    // lane holds S[t=16wv+orow+rr][s=16nt+lrow]; mask+scale -> SL bf16
    #pragma unroll
    for (int rr = 0; rr < 4; ++rr) {
        int t = 16 * wv + orow + rr;
        float etv = __expf(Ah * (angs[t] - aend));   // >= 1
        #pragma unroll
        for (int nt = 0; nt < 4; ++nt) {
            int s = 16 * nt + lrow;
            float v = (t >= s) ? accS[nt][rr] * etv : 0.f;
            SL[t][s] = f2bf(v);
        }
    }
    __syncthreads();  // SL + uwT visible

    // ---- Phase 2: y_intra = SL . uwT^T ; out = 4*y + D*x ----
    {
        f32x4 accY[4] = {{0.f,0.f,0.f,0.f},{0.f,0.f,0.f,0.f},
                         {0.f,0.f,0.f,0.f},{0.f,0.f,0.f,0.f}};
        #pragma unroll
        for (int kk = 0; kk < 2; ++kk) {
            int k0 = kk * 32;
            short8 a = *(const short8*)(&SL[16 * wv + lrow][k0 + kgrp]);
            #pragma unroll
            for (int nt = 0; nt < 4; ++nt) {
                short8 bfr = *(const short8*)(&uwT[16 * nt + lrow][k0 + kgrp]);
                accY[nt] = __builtin_amdgcn_mfma_f32_16x16x32_bf16(
                    a, bfr, accY[nt], 0, 0, 0);
            }
        }
        float Dh = Dd[h];
        #pragma unroll
        for (int nt = 0; nt < 4; ++nt) {
            int e = 16 * nt + lrow;
            #pragma unroll
            for (int rr = 0; rr < 4; ++rr) {
                int t = 16 * wv + orow + rr;
                size_t oidx = ((((size_t)b * LL + t0 + t) * HH) + h) * DV + e;
                out[oidx] = MIMO_RANK * accY[nt][rr] + Dh * x[oidx];
            }
        }
    }

    // ---- Phase 3: dH = rkT . uwT^T (m=d, n=e, K=64) ----
    {
        f32x4 accH[2][4] = {{{0.f,0.f,0.f,0.f},{0.f,0.f,0.f,0.f},
                             {0.f,0.f,0.f,0.f},{0.f,0.f,0.f,0.f}},
                            {{0.f,0.f,0.f,0.f},{0.f,0.f,0.f,0.f},
                             {0.f,0.f,0.f,0.f},{0.f,0.f,0.f,0.f}}};
        #pragma unroll
        for (int kk = 0; kk < 2; ++kk) {
            int k0 = kk * 32;
            #pragma unroll
            for (int mt = 0; mt < 2; ++mt) {
                short8 a = *(const short8*)(&rkT[32 * wv + 16 * mt + lrow][k0 + kgrp]);
                #pragma unroll
                for (int nt = 0; nt < 4; ++nt) {
                    short8 bfr = *(const short8*)(&uwT[16 * nt + lrow][k0 + kgrp]);
                    accH[mt][nt] = __builtin_amdgcn_mfma_f32_16x16x32_bf16(
                        a, bfr, accH[mt][nt], 0, 0, 0);
                }
            }
        }
        __syncthreads();  // all rkT reads done -> safe to reuse as dstage
        ushort* dstage = &rkT[0][0];  // [64][136], e-major
        #pragma unroll
        for (int mt = 0; mt < 2; ++mt) {
            #pragma unroll
            for (int nt = 0; nt < 4; ++nt) {
                int e = 16 * nt + lrow;
                #pragma unroll
                for (int rr = 0; rr < 4; ++rr) {
                    int d = 32 * wv + 16 * mt + orow + rr;
                    dstage[e * 136 + d] = f2bf(accH[mt][nt][rr]);
                }
            }
        }
        __syncthreads();
        // coalesced flush: dH tile stored [e][d] bf16
        ushort* dHp = dH + (((size_t)(b * NN + n) * HH) + h) * (DQK * DV);
        for (int idx = tid; idx < DQK * DV / 8; idx += 256) {  // 4 iters
            int e = idx >> 4, c8 = (idx & 15) * 8;
            *(short8*)(dHp + (size_t)idx * 8) =
                *(const short8*)(&dstage[e * 136 + c8]);
        }
    }
}

// ---------------------------------------------------------------------------
// K3: sequential chunk scan, in place, bf16 pairs, f32 accumulators.
// dH layout: [b][n][h][e][d] bf16; per-(b,n) plane = 2^17 pairs.
// ---------------------------------------------------------------------------
__global__ __launch_bounds__(256) void k_scan_chunks(
    uint* __restrict__ dH, const float* __restrict__ cdecay) {
    uint f = blockIdx.x * 256 + threadIdx.x;   // 0..262143
    int b = (int)(f >> 17);
    uint r = f & 0x1FFFF;
    int h = (int)((r >> 12) & 31);
    uint base = ((uint)b << 23) | r;
    const float* cd = cdecay + (size_t)b * NN * HH + h;
    float h0 = 0.f, h1 = 0.f;
    for (int n = 0; n < NN; ++n) {
        uint a = base + ((uint)n << 17);
        uint v = dH[a];
        float v0 = bfbits2f(v & 0xFFFF), v1 = bfbits2f(v >> 16);
        dH[a] = packbf2(h0, h1);       // Hprev for chunk n
        float c = cd[n * HH];
        h0 = c * h0 + v0;
        h1 = c * h1 + v1;
    }
}

// ---------------------------------------------------------------------------
// K4: y_inter + final combine.
// y_inter = rq(frags) . Hprev^T : A=rq[t][d] (regs), B=HpT[e][d] (LDS), K=128
// out += 4 * exp(cum_t) * y_inter
// ---------------------------------------------------------------------------
__global__ __launch_bounds__(256, 4) void k_inter(
    const float* __restrict__ A, const float* __restrict__ Cg,
    const float* __restrict__ ang, const ushort* __restrict__ Hprev,
    float* __restrict__ out) {
    int n = blockIdx.x, h = blockIdx.y, b = blockIdx.z;
    int tid = threadIdx.x;
    int t0 = n * CC;

    __shared__ ushort HpT[DV][DQK + 8];   // [e][d] (same as global layout)
    __shared__ float csv[CC], ssv[CC], gs[CC], angs[CC];
    __shared__ float angPrev_s;

    float Ah = A[h];
    if (tid < CC) {
        float a = ang[(((size_t)b * LL + t0 + tid) * HH) + h];
        angs[tid] = a;
        float sv, cv;
        __sincosf(a, &sv, &cv);
        csv[tid] = cv;
        ssv[tid] = sv;
    }
    if (tid == 0)
        angPrev_s = (t0 == 0) ? 0.f : ang[(((size_t)b * LL + t0 - 1) * HH) + h];
    __syncthreads();
    if (tid < CC) gs[tid] = __expf(Ah * (angs[tid] - angPrev_s));

    // stage Hprev tile (already [e][d]) -> LDS, coalesced
    const ushort* Hsrc = Hprev + (((size_t)(b * NN + n) * HH) + h) * (DQK * DV);
    for (int idx = tid; idx < DQK * DV / 2; idx += 256) {  // 16 iters
        uint v = *(const uint*)(Hsrc + (size_t)idx * 2);
        int e = idx >> 6, d2 = (idx & 63) * 2;
        *(uint*)(&HpT[e][d2]) = v;
    }

    int wv = tid >> 6, lane = tid & 63;
    int lrow = lane & 15;
    int kgrp = (lane >> 4) * 8;
    int orow = (lane >> 4) * 4;

    int t_own = 16 * wv + lrow;
    short8 aq[4];
    make_rot_frags(Cg, ((size_t)b * LL + t0 + t_own) * DQK,
                   csv[t_own], ssv[t_own], kgrp, aq);
    __syncthreads();

    f32x4 accI[4] = {{0.f,0.f,0.f,0.f},{0.f,0.f,0.f,0.f},
                     {0.f,0.f,0.f,0.f},{0.f,0.f,0.f,0.f}};
    #pragma unroll
    for (int kk = 0; kk < 4; ++kk) {
        int k0 = kk * 32;
        #pragma unroll
        for (int nt = 0; nt < 4; ++nt) {
            short8 bfr = *(const short8*)(&HpT[16 * nt + lrow][k0 + kgrp]);
            accI[nt] = __builtin_amdgcn_mfma_f32_16x16x32_bf16(
                aq[kk], bfr, accI[nt], 0, 0, 0);
        }
    }

    #pragma unroll
    for (int rr = 0; rr < 4; ++rr) {
        int t = 16 * wv + orow + rr;
        float g4 = MIMO_RANK * gs[t];
        #pragma unroll
        for (int nt = 0; nt < 4; ++nt) {
            int e = 16 * nt + lrow;
            size_t oidx = ((((size_t)b * LL + t0 + t) * HH) + h) * DV + e;
            out[oidx] += g4 * accI[nt][rr];
        }
    }
}

// ---------------------------------------------------------------------------
extern "C" void kernel_launch(void* const* d_in, const int* in_sizes, int n_in,
                              void* d_out, int out_size, void* d_ws,
                              size_t ws_size, hipStream_t stream) {
    (void)in_sizes; (void)n_in; (void)out_size; (void)ws_size;
    const float* x  = (const float*)d_in[0];
    const float* dt = (const float*)d_in[1];
    const float* A  = (const float*)d_in[2];
    const float* Bg = (const float*)d_in[3];
    const float* Cg = (const float*)d_in[4];
    const float* Dd = (const float*)d_in[5];
    float* out = (float*)d_out;
    float* ws  = (float*)d_ws;

    float*  ang    = ws;                       // B*L*H       = 262144 f32
    float*  cdecay = ws + 262144;              // B*N*H       = 4096 f32
    ushort* dH     = (ushort*)(ws + 266240);   // B*N*H*DQK*DV bf16 (67 MB)

    k_scan_dt<<<BB * HH, 256, 0, stream>>>(dt, ang);
    k_intra<<<dim3(NN, HH, BB), 256, 0, stream>>>(x, dt, A, Bg, Cg, ang, Dd,
                                                  out, dH, cdecay);
    k_scan_chunks<<<(BB * HH * DQK * DV / 2) / 256, 256, 0, stream>>>(
        (uint*)dH, cdecay);
    k_inter<<<dim3(NN, HH, BB), 256, 0, stream>>>(A, Cg, ang, dH, out);
}

// Round 5
// 113.648 us; speedup vs baseline: 12.7889x; 1.2348x over previous
//
#include <hip/hip_runtime.h>
#include <hip/hip_bf16.h>

// Problem constants (fixed by setup_inputs)
#define BB 2
#define LL 4096
#define HH 32
#define DV 64
#define DQK 128
#define CC 64            // chunk size
#define NN 64            // number of chunks = LL/CC
#define MIMO_RANK 4.0f

typedef __attribute__((ext_vector_type(8))) short short8;
typedef __attribute__((ext_vector_type(4))) float f32x4;

__device__ __forceinline__ ushort f2bf(float f) {
    uint u = __float_as_uint(f);
    u += 0x7FFF + ((u >> 16) & 1);   // RNE
    return (ushort)(u >> 16);
}
__device__ __forceinline__ float bfbits2f(uint lo16) {
    return __uint_as_float(lo16 << 16);
}
// pack two f32 -> two bf16 (lo -> bits[15:0], hi -> bits[31:16]), RNE
__device__ __forceinline__ uint pkbf2(float lo, float hi) {
    return (uint)f2bf(lo) | ((uint)f2bf(hi) << 16);
}
union U8 { uint u[4]; short8 s; };

// ---- LDS swizzled-offset helpers (element offsets in ushorts) ----
// rk: [64 s][128 d], 16 slots/row, slot ^= (s&7)
__device__ __forceinline__ int rk_off(int s, int d) {
    return s * 128 + (((((d >> 3) & 15) ^ (s & 7)) << 3)) + (d & 7);
}
// rkT: [128 d][64 s], 8 slots/row, slot ^= (d&7)
__device__ __forceinline__ int rkT_off(int d, int s) {
    return d * 64 + ((((s >> 3) ^ (d & 7)) & 7) << 3) + (s & 7);
}
// uwT: [64 e][64 s], slot ^= (e&7)
__device__ __forceinline__ int uwT_off(int e, int s) {
    return e * 64 + ((((s >> 3) ^ (e & 7)) & 7) << 3) + (s & 7);
}
// SL: [64 t][64 s], slot ^= fSL(t)
__device__ __forceinline__ int fSL(int t) {
    return (((t & 3) << 1) ^ ((t >> 2) & 7)) & 7;
}
__device__ __forceinline__ int SL_off(int t, int s) {
    return t * 64 + ((((s >> 3) ^ fSL(t)) & 7) << 3) + (s & 7);
}

// Build the 4 A-fragments (K=128) of a rotary-transformed row in registers.
__device__ __forceinline__ void make_rot_frags(const float* __restrict__ G,
                                               size_t gb, float cv, float sv,
                                               int kgrp, short8* fr) {
    #pragma unroll
    for (int kk = 0; kk < 4; ++kk) {
        int d0 = kk * 32 + kgrp;
        int dl = d0 & 63;
        bool low = d0 < 64;
        float4 a1 = *(const float4*)(G + gb + dl);
        float4 b1 = *(const float4*)(G + gb + dl + 4);
        float4 a2 = *(const float4*)(G + gb + dl + 64);
        float4 b2 = *(const float4*)(G + gb + dl + 68);
        float v0, v1, v2, v3, v4, v5, v6, v7;
        if (low) {
            v0 = a1.x * cv - a2.x * sv; v1 = a1.y * cv - a2.y * sv;
            v2 = a1.z * cv - a2.z * sv; v3 = a1.w * cv - a2.w * sv;
            v4 = b1.x * cv - b2.x * sv; v5 = b1.y * cv - b2.y * sv;
            v6 = b1.z * cv - b2.z * sv; v7 = b1.w * cv - b2.w * sv;
        } else {
            v0 = a1.x * sv + a2.x * cv; v1 = a1.y * sv + a2.y * cv;
            v2 = a1.z * sv + a2.z * cv; v3 = a1.w * sv + a2.w * cv;
            v4 = b1.x * sv + b2.x * cv; v5 = b1.y * sv + b2.y * cv;
            v6 = b1.z * sv + b2.z * cv; v7 = b1.w * sv + b2.w * cv;
        }
        U8 r;
        r.u[0] = pkbf2(v0, v1); r.u[1] = pkbf2(v2, v3);
        r.u[2] = pkbf2(v4, v5); r.u[3] = pkbf2(v6, v7);
        fr[kk] = r.s;
    }
}

// ---------------------------------------------------------------------------
// K1: full-sequence inclusive prefix sum of dt over l, per (b,h).
// ---------------------------------------------------------------------------
__global__ __launch_bounds__(256) void k_scan_dt(const float* __restrict__ dt,
                                                 float* __restrict__ ang) {
    int bh = blockIdx.x;
    int b = bh / HH, h = bh % HH;
    int tid = threadIdx.x;
    const int PT = LL / 256;  // 16
    float v[PT];
    float s = 0.f;
    int tbase = tid * PT;
    for (int i = 0; i < PT; ++i) {
        v[i] = dt[(((size_t)b * LL + tbase + i) * HH) + h];
        s += v[i];
    }
    int lane = tid & 63, wv = tid >> 6;
    float ps = s;
    for (int off = 1; off < 64; off <<= 1) {
        float o = __shfl_up(ps, off, 64);
        if (lane >= off) ps += o;
    }
    __shared__ float wsum[4];
    if (lane == 63) wsum[wv] = ps;
    __syncthreads();
    float wadd = 0.f;
    for (int w = 0; w < wv; ++w) wadd += wsum[w];
    float run = wadd + ps - s;
    for (int i = 0; i < PT; ++i) {
        run += v[i];
        ang[(((size_t)b * LL + tbase + i) * HH) + h] = run;
    }
}

// ---------------------------------------------------------------------------
// K2: per-(b,n,h) intra-chunk tile, MFMA, swizzled LDS, 3 barriers.
// dH tile stored to global in a fixed PERMUTED layout (16 rows x 64 lanes x
// 16B): row R = wv*4+q (q: mt=q>>1, np=q&1), lane l = 16g+lrow; uint j of
// (R,l) holds (d = 32wv+16mt+4g+{2(j&1),2(j&1)+1}, e = 32np+16(j>>1)+lrow).
// ---------------------------------------------------------------------------
__global__ __launch_bounds__(256, 3) void k_intra(
    const float* __restrict__ x, const float* __restrict__ dt,
    const float* __restrict__ A, const float* __restrict__ Bg,
    const float* __restrict__ Cg, const float* __restrict__ ang,
    const float* __restrict__ Dd,
    float* __restrict__ out, ushort* __restrict__ dH,
    float* __restrict__ cdecay) {
    int n = blockIdx.x, h = blockIdx.y, b = blockIdx.z;
    int tid = threadIdx.x;
    int t0 = n * CC;

    __shared__ ushort rkS[CC * DQK];    // 16384 B
    __shared__ ushort rkT[DQK * CC];    // 16384 B
    __shared__ ushort uwT[DV * CC];     // 8192 B
    __shared__ ushort SLs[CC * CC];     // 8192 B
    __shared__ float angs[CC], csv[CC], ssv[CC], dw2[CC];
    // total ~51 KB -> 3 blocks/CU

    float Ah = A[h];

    float my_dt = 0.f;
    if (tid < CC) {
        float a = ang[(((size_t)b * LL + t0 + tid) * HH) + h];
        angs[tid] = a;
        float sv, cv;
        __sincosf(a, &sv, &cv);
        csv[tid] = cv;
        ssv[tid] = sv;
        my_dt = dt[(((size_t)b * LL + t0 + tid) * HH) + h];
    }
    __syncthreads();  // sync-1: angs/csv/ssv ready
    float aend = angs[CC - 1];
    if (tid < CC) {
        dw2[tid] = my_dt * __expf(Ah * (aend - angs[tid]));
    }
    if (tid == 0) {
        float angPrev = (t0 == 0) ? 0.f
                                  : ang[(((size_t)b * LL + t0 - 1) * HH) + h];
        cdecay[(b * NN + n) * HH + h] = __expf(Ah * (aend - angPrev));
    }

    // ---- stage rk (swizzled, b128 writes only) ----
    #pragma unroll
    for (int it = 0; it < 2; ++it) {
        int w = tid + 256 * it;          // 0..511
        int s = w >> 3, oct = w & 7;     // d0 = 8*oct (low half), +64 high
        size_t gb = ((size_t)b * LL + t0 + s) * DQK;
        const float* p = Bg + gb + 8 * oct;
        float4 a0 = *(const float4*)(p);
        float4 a1 = *(const float4*)(p + 4);
        float4 b0 = *(const float4*)(p + 64);
        float4 b1 = *(const float4*)(p + 68);
        float cv = csv[s], sv = ssv[s];
        U8 lo, hi;
        lo.u[0] = pkbf2(a0.x * cv - b0.x * sv, a0.y * cv - b0.y * sv);
        lo.u[1] = pkbf2(a0.z * cv - b0.z * sv, a0.w * cv - b0.w * sv);
        lo.u[2] = pkbf2(a1.x * cv - b1.x * sv, a1.y * cv - b1.y * sv);
        lo.u[3] = pkbf2(a1.z * cv - b1.z * sv, a1.w * cv - b1.w * sv);
        hi.u[0] = pkbf2(a0.x * sv + b0.x * cv, a0.y * sv + b0.y * cv);
        hi.u[1] = pkbf2(a0.z * sv + b0.z * cv, a0.w * sv + b0.w * cv);
        hi.u[2] = pkbf2(a1.x * sv + b1.x * cv, a1.y * sv + b1.y * cv);
        hi.u[3] = pkbf2(a1.z * sv + b1.z * cv, a1.w * sv + b1.w * cv);
        *(short8*)&rkS[rk_off(s, 8 * oct)] = lo.s;
        *(short8*)&rkS[rk_off(s, 8 * oct + 64)] = hi.s;
    }

    int wv = tid >> 6, lane = tid & 63;
    int lrow = lane & 15;
    int g = lane >> 4;
    int kgrp = g * 8;
    int orow = g * 4;

    // rq A-fragments in registers (wave wv owns t rows [16wv,16wv+16))
    int t_own = 16 * wv + lrow;
    short8 aq[4];
    make_rot_frags(Cg, ((size_t)b * LL + t0 + t_own) * DQK,
                   csv[t_own], ssv[t_own], kgrp, aq);

    __syncthreads();  // sync-2: rk + dw2 ready

    // ---- stage uwT (transposed; scalar global loads -> b128 write) ----
    #pragma unroll
    for (int it = 0; it < 2; ++it) {
        int w = tid + 256 * it;          // 0..511
        int e = w & 63, soct = w >> 6;   // s0 = 8*soct
        int s0 = 8 * soct;
        U8 pk;
        #pragma unroll
        for (int jp = 0; jp < 4; ++jp) {
            int s_a = s0 + 2 * jp, s_b = s_a + 1;
            float xa = x[((((size_t)b * LL + t0 + s_a) * HH) + h) * DV + e] * dw2[s_a];
            float xb = x[((((size_t)b * LL + t0 + s_b) * HH) + h) * DV + e] * dw2[s_b];
            pk.u[jp] = pkbf2(xa, xb);
        }
        *(short8*)&uwT[uwT_off(e, s0)] = pk.s;
    }
    // ---- build rkT from rk (transposed scalar reads -> b128 write) ----
    #pragma unroll
    for (int it = 0; it < 4; ++it) {
        int w = tid + 256 * it;          // 0..1023
        int d = w & 127, soct = w >> 7;  // s0 = 8*soct
        int s0 = 8 * soct;
        uint v[8];
        #pragma unroll
        for (int j = 0; j < 8; ++j) v[j] = rkS[rk_off(s0 + j, d)];
        U8 pk;
        pk.u[0] = v[0] | (v[1] << 16);
        pk.u[1] = v[2] | (v[3] << 16);
        pk.u[2] = v[4] | (v[5] << 16);
        pk.u[3] = v[6] | (v[7] << 16);
        *(short8*)&rkT[rkT_off(d, s0)] = pk.s;
    }

    // ---- Phase 1: S = rq . rk^T (m = t-rows of wave, n = s, K = 128) ----
    f32x4 accS[4] = {{0.f,0.f,0.f,0.f},{0.f,0.f,0.f,0.f},
                     {0.f,0.f,0.f,0.f},{0.f,0.f,0.f,0.f}};
    #pragma unroll
    for (int kk = 0; kk < 4; ++kk) {
        #pragma unroll
        for (int nt = 0; nt < 4; ++nt) {
            int s = 16 * nt + lrow;
            const short8 bfr = *(const short8*)&rkS[rk_off(s, 32 * kk + kgrp)];
            accS[nt] = __builtin_amdgcn_mfma_f32_16x16x32_bf16(
                aq[kk], bfr, accS[nt], 0, 0, 0);
        }
    }
    // mask + scale -> SL (scalar b16 writes, swizzled)
    #pragma unroll
    for (int rr = 0; rr < 4; ++rr) {
        int t = 16 * wv + orow + rr;
        float etv = __expf(Ah * (angs[t] - aend));
        #pragma unroll
        for (int nt = 0; nt < 4; ++nt) {
            int s = 16 * nt + lrow;
            float v = (t >= s) ? accS[nt][rr] * etv : 0.f;
            SLs[SL_off(t, s)] = f2bf(v);
        }
    }
    __syncthreads();  // sync-3: SL + uwT + rkT ready

    // ---- Phase 2: y_intra = SL . uwT^T ; out = 4*y + D*x ----
    {
        f32x4 accY[4] = {{0.f,0.f,0.f,0.f},{0.f,0.f,0.f,0.f},
                         {0.f,0.f,0.f,0.f},{0.f,0.f,0.f,0.f}};
        #pragma unroll
        for (int kk = 0; kk < 2; ++kk) {
            const short8 a = *(const short8*)&SLs[SL_off(16 * wv + lrow, 32 * kk + kgrp)];
            #pragma unroll
            for (int nt = 0; nt < 4; ++nt) {
                const short8 bfr = *(const short8*)&uwT[uwT_off(16 * nt + lrow, 32 * kk + kgrp)];
                accY[nt] = __builtin_amdgcn_mfma_f32_16x16x32_bf16(
                    a, bfr, accY[nt], 0, 0, 0);
            }
        }
        float Dh = Dd[h];
        #pragma unroll
        for (int nt = 0; nt < 4; ++nt) {
            int e = 16 * nt + lrow;
            #pragma unroll
            for (int rr = 0; rr < 4; ++rr) {
                int t = 16 * wv + orow + rr;
                size_t oidx = ((((size_t)b * LL + t0 + t) * HH) + h) * DV + e;
                out[oidx] = MIMO_RANK * accY[nt][rr] + Dh * x[oidx];
            }
        }
    }

    // ---- Phase 3: dH = rkT . uwT^T (m = d, n = e, K = 64) ----
    {
        f32x4 accH[2][4] = {{{0.f,0.f,0.f,0.f},{0.f,0.f,0.f,0.f},
                             {0.f,0.f,0.f,0.f},{0.f,0.f,0.f,0.f}},
                            {{0.f,0.f,0.f,0.f},{0.f,0.f,0.f,0.f},
                             {0.f,0.f,0.f,0.f},{0.f,0.f,0.f,0.f}}};
        #pragma unroll
        for (int kk = 0; kk < 2; ++kk) {
            #pragma unroll
            for (int mt = 0; mt < 2; ++mt) {
                const short8 a = *(const short8*)&rkT[rkT_off(32 * wv + 16 * mt + lrow, 32 * kk + kgrp)];
                #pragma unroll
                for (int nt = 0; nt < 4; ++nt) {
                    const short8 bfr = *(const short8*)&uwT[uwT_off(16 * nt + lrow, 32 * kk + kgrp)];
                    accH[mt][nt] = __builtin_amdgcn_mfma_f32_16x16x32_bf16(
                        a, bfr, accH[mt][nt], 0, 0, 0);
                }
            }
        }
        // direct permuted global store: 16B per lane per q, fully coalesced
        ushort* dHp = dH + (((size_t)(b * NN + n) * HH) + h) * (DQK * DV);
        #pragma unroll
        for (int q = 0; q < 4; ++q) {
            int mt = q >> 1, np = q & 1;
            U8 st;
            st.u[0] = pkbf2(accH[mt][2 * np][0], accH[mt][2 * np][1]);
            st.u[1] = pkbf2(accH[mt][2 * np][2], accH[mt][2 * np][3]);
            st.u[2] = pkbf2(accH[mt][2 * np + 1][0], accH[mt][2 * np + 1][1]);
            st.u[3] = pkbf2(accH[mt][2 * np + 1][2], accH[mt][2 * np + 1][3]);
            *(short8*)(dHp + ((size_t)(wv * 4 + q) * 64 + lane) * 8) = st.s;
        }
    }
}

// ---------------------------------------------------------------------------
// K3: sequential chunk scan, in place, bf16 pairs, f32 accumulators.
// Layout-agnostic elementwise over each (b,n,h) 4096-uint tile.
// ---------------------------------------------------------------------------
__global__ __launch_bounds__(256) void k_scan_chunks(
    uint* __restrict__ dH, const float* __restrict__ cdecay) {
    uint f = blockIdx.x * 256 + threadIdx.x;   // 0..262143
    int b = (int)(f >> 17);
    uint r = f & 0x1FFFF;
    int h = (int)((r >> 12) & 31);
    uint base = ((uint)b << 23) | r;
    const float* cd = cdecay + (size_t)b * NN * HH + h;
    float h0 = 0.f, h1 = 0.f;
    for (int n = 0; n < NN; ++n) {
        uint a = base + ((uint)n << 17);
        uint v = dH[a];
        float v0 = bfbits2f(v & 0xFFFF), v1 = bfbits2f(v >> 16);
        dH[a] = pkbf2(h0, h1);       // Hprev for chunk n
        float c = cd[n * HH];
        h0 = c * h0 + v0;
        h1 = c * h1 + v1;
    }
}

// ---------------------------------------------------------------------------
// K4: y_inter + final combine. Hprev tile is in the k_intra permuted layout;
// staged to LDS with EVEN row stride (260 uints = 1040 B, 16B-aligned rows);
// B-frags rebuilt with 2x 8B-aligned uint2 reads.
// ---------------------------------------------------------------------------
__global__ __launch_bounds__(256, 4) void k_inter(
    const float* __restrict__ A, const float* __restrict__ Cg,
    const float* __restrict__ ang, const ushort* __restrict__ Hprev,
    float* __restrict__ out) {
    int n = blockIdx.x, h = blockIdx.y, b = blockIdx.z;
    int tid = threadIdx.x;
    int t0 = n * CC;

    __shared__ __align__(16) uint Hp[16 * 260];  // rows 16B-aligned
    __shared__ float csv[CC], ssv[CC], gs[CC], angs[CC];
    __shared__ float angPrev_s;

    float Ah = A[h];
    if (tid < CC) {
        float a = ang[(((size_t)b * LL + t0 + tid) * HH) + h];
        angs[tid] = a;
        float sv, cv;
        __sincosf(a, &sv, &cv);
        csv[tid] = cv;
        ssv[tid] = sv;
    }
    if (tid == 0)
        angPrev_s = (t0 == 0) ? 0.f : ang[(((size_t)b * LL + t0 - 1) * HH) + h];
    __syncthreads();
    if (tid < CC) gs[tid] = __expf(Ah * (angs[tid] - angPrev_s));

    // stage Hprev tile (4096 uints) -> LDS, aligned uint4 writes
    const uint* Hsrc = (const uint*)(Hprev + (((size_t)(b * NN + n) * HH) + h) * (DQK * DV));
    #pragma unroll
    for (int it = 0; it < 4; ++it) {
        int p = tid + 256 * it;          // 0..1023 (uint4 index)
        uint4 v = *(const uint4*)(Hsrc + (size_t)p * 4);
        int row = p >> 6, c = p & 63;
        uint4* Hrow = (uint4*)&Hp[row * 260];   // 260*4 = 65*16 -> aligned
        Hrow[c] = v;
    }

    int wv = tid >> 6, lane = tid & 63;
    int lrow = lane & 15;
    int g2 = lane >> 4;
    int kgrp = g2 * 8;
    int orow = g2 * 4;

    int t_own = 16 * wv + lrow;
    short8 aq[4];
    make_rot_frags(Cg, ((size_t)b * LL + t0 + t_own) * DQK,
                   csv[t_own], ssv[t_own], kgrp, aq);
    __syncthreads();

    f32x4 accI[4] = {{0.f,0.f,0.f,0.f},{0.f,0.f,0.f,0.f},
                     {0.f,0.f,0.f,0.f},{0.f,0.f,0.f,0.f}};
    int mt = g2 >> 1;
    int gp0 = 2 * (g2 & 1);
    #pragma unroll
    for (int kk = 0; kk < 4; ++kk) {
        #pragma unroll
        for (int nt = 0; nt < 4; ++nt) {
            int q = mt * 2 + (nt >> 1);
            int row = kk * 4 + q;
            int sb = (nt & 1) * 2;
            const uint2 u0 = *(const uint2*)&Hp[row * 260 + (16 * gp0 + lrow) * 4 + sb];
            const uint2 u1 = *(const uint2*)&Hp[row * 260 + (16 * (gp0 + 1) + lrow) * 4 + sb];
            U8 fr;
            fr.u[0] = u0.x; fr.u[1] = u0.y; fr.u[2] = u1.x; fr.u[3] = u1.y;
            accI[nt] = __builtin_amdgcn_mfma_f32_16x16x32_bf16(
                aq[kk], fr.s, accI[nt], 0, 0, 0);
        }
    }

    #pragma unroll
    for (int rr = 0; rr < 4; ++rr) {
        int t = 16 * wv + orow + rr;
        float g4 = MIMO_RANK * gs[t];
        #pragma unroll
        for (int nt = 0; nt < 4; ++nt) {
            int e = 16 * nt + lrow;
            size_t oidx = ((((size_t)b * LL + t0 + t) * HH) + h) * DV + e;
            out[oidx] += g4 * accI[nt][rr];
        }
    }
}

// ---------------------------------------------------------------------------
extern "C" void kernel_launch(void* const* d_in, const int* in_sizes, int n_in,
                              void* d_out, int out_size, void* d_ws,
                              size_t ws_size, hipStream_t stream) {
    (void)in_sizes; (void)n_in; (void)out_size; (void)ws_size;
    const float* x  = (const float*)d_in[0];
    const float* dt = (const float*)d_in[1];
    const float* A  = (const float*)d_in[2];
    const float* Bg = (const float*)d_in[3];
    const float* Cg = (const float*)d_in[4];
    const float* Dd = (const float*)d_in[5];
    float* out = (float*)d_out;
    float* ws  = (float*)d_ws;

    float*  ang    = ws;                       // B*L*H       = 262144 f32
    float*  cdecay = ws + 262144;              // B*N*H       = 4096 f32
    ushort* dH     = (ushort*)(ws + 266240);   // B*N*H*DQK*DV bf16 (67 MB)

    k_scan_dt<<<BB * HH, 256, 0, stream>>>(dt, ang);
    k_intra<<<dim3(NN, HH, BB), 256, 0, stream>>>(x, dt, A, Bg, Cg, ang, Dd,
                                                  out, dH, cdecay);
    k_scan_chunks<<<(BB * HH * DQK * DV / 2) / 256, 256, 0, stream>>>(
        (uint*)dH, cdecay);
    k_inter<<<dim3(NN, HH, BB), 256, 0, stream>>>(A, Cg, ang, dH, out);
}